// Round 1
// baseline (614.092 us; speedup 1.0000x reference)
//
#include <hip/hip_runtime.h>
#include <math.h>

#define IN_DIM 128
#define HEADS 8
#define HID 16
#define OUT_DIM 40
#define NEG 0.2f

// ---------------- CSR build ----------------

__global__ void zero_ints(int* p, int n) {
  int i = blockIdx.x * blockDim.x + threadIdx.x;
  if (i < n) p[i] = 0;
}

__global__ void hist_k(const int* __restrict__ ei, int E0, int N, int* __restrict__ deg) {
  int e = blockIdx.x * blockDim.x + threadIdx.x;
  int EP = E0 + N;
  if (e >= EP) return;
  int d = (e < E0) ? ei[E0 + e] : (e - E0);
  atomicAdd(&deg[d], 1);
}

// single-block exclusive scan, 1024 threads, wave shfl scans
__global__ void scan_k(const int* __restrict__ deg, int* __restrict__ row_ptr, int n) {
  __shared__ int wsum[16];
  __shared__ int carry_s;
  int tid = threadIdx.x;
  int lane = tid & 63;
  int w = tid >> 6;
  if (tid == 0) carry_s = 0;
  __syncthreads();
  for (int base = 0; base < n; base += 1024) {
    int i = base + tid;
    int v = (i < n) ? deg[i] : 0;
    int x = v;
    #pragma unroll
    for (int off = 1; off < 64; off <<= 1) {
      int y = __shfl_up(x, off);
      if (lane >= off) x += y;
    }
    if (lane == 63) wsum[w] = x;
    __syncthreads();
    if (tid < 16) {
      int s = wsum[tid];
      #pragma unroll
      for (int off = 1; off < 16; off <<= 1) {
        int y = __shfl_up(s, off);
        if (tid >= off) s += y;
      }
      wsum[tid] = s;  // inclusive over wave sums
    }
    __syncthreads();
    int waveoff = (w == 0) ? 0 : wsum[w - 1];
    int incl = x + waveoff;
    int carry = carry_s;
    int total = wsum[15];
    if (i < n) row_ptr[i] = carry + incl - v;  // exclusive
    __syncthreads();
    if (tid == 0) carry_s = carry + total;
    __syncthreads();
  }
  if (threadIdx.x == 0) row_ptr[n] = carry_s;
}

__global__ void scatter_k(const int* __restrict__ ei, int E0, int N,
                          const int* __restrict__ row_ptr, int* __restrict__ cnt,
                          int* __restrict__ csr_src) {
  int e = blockIdx.x * blockDim.x + threadIdx.x;
  int EP = E0 + N;
  if (e >= EP) return;
  int s, d;
  if (e < E0) { s = ei[e]; d = ei[E0 + e]; } else { s = e - E0; d = s; }
  int pos = row_ptr[d] + atomicAdd(&cnt[d], 1);
  csr_src[pos] = s;
}

// ---------------- GEMM1: h1 = x @ W1, plus a1s/a1d ----------------
// 128 rows/block, 256 threads, K-tiles of 32. x tile stored transposed (conflict-free).
__global__ __launch_bounds__(256) void gemm1_k(
    const float* __restrict__ x, const float* __restrict__ W1,
    const float* __restrict__ att_s, const float* __restrict__ att_d,
    float* __restrict__ h1, float* __restrict__ a1s, float* __restrict__ a1d, int N) {
  __shared__ float xsT[32][129];
  __shared__ float w1s[32][128];
  int tid = threadIdx.x;
  int rowbase = blockIdx.x * 128;
  int r0 = tid & 31;
  int h = tid >> 5;  // 0..7
  float acc[4][16];
  #pragma unroll
  for (int a = 0; a < 4; ++a)
    #pragma unroll
    for (int j = 0; j < 16; ++j) acc[a][j] = 0.f;

  for (int kt = 0; kt < 4; ++kt) {
    #pragma unroll
    for (int i = 0; i < 16; ++i) {
      int idx = tid + i * 256;
      int kk = idx >> 7, c = idx & 127;
      w1s[kk][c] = W1[(kt * 32 + kk) * 128 + c];
    }
    #pragma unroll
    for (int i = 0; i < 16; ++i) {
      int idx = tid + i * 256;
      int kk = idx & 31, r = idx >> 5;
      int row = rowbase + r;
      xsT[kk][r] = (row < N) ? x[row * 128 + kt * 32 + kk] : 0.f;
    }
    __syncthreads();
    #pragma unroll
    for (int kk = 0; kk < 32; ++kk) {
      float xv[4];
      #pragma unroll
      for (int a = 0; a < 4; ++a) xv[a] = xsT[kk][r0 + a * 32];
      const float4* wr = reinterpret_cast<const float4*>(&w1s[kk][h * 16]);
      #pragma unroll
      for (int q = 0; q < 4; ++q) {
        float4 wv = wr[q];
        #pragma unroll
        for (int a = 0; a < 4; ++a) {
          acc[a][q * 4 + 0] += xv[a] * wv.x;
          acc[a][q * 4 + 1] += xv[a] * wv.y;
          acc[a][q * 4 + 2] += xv[a] * wv.z;
          acc[a][q * 4 + 3] += xv[a] * wv.w;
        }
      }
    }
    __syncthreads();
  }
  float as[16], ad[16];
  #pragma unroll
  for (int j = 0; j < 16; ++j) { as[j] = att_s[h * 16 + j]; ad[j] = att_d[h * 16 + j]; }
  #pragma unroll
  for (int a = 0; a < 4; ++a) {
    int row = rowbase + r0 + a * 32;
    if (row < N) {
      float ss = 0.f, sd = 0.f;
      #pragma unroll
      for (int j = 0; j < 16; ++j) { ss += acc[a][j] * as[j]; sd += acc[a][j] * ad[j]; }
      float4* out4 = reinterpret_cast<float4*>(&h1[row * 128 + h * 16]);
      #pragma unroll
      for (int q = 0; q < 4; ++q)
        out4[q] = make_float4(acc[a][q * 4 + 0], acc[a][q * 4 + 1], acc[a][q * 4 + 2], acc[a][q * 4 + 3]);
      a1s[row * 8 + h] = ss;
      a1d[row * 8 + h] = sd;
    }
  }
}

// ---------------- Layer-1 aggregation + ELU + fused GEMM2 row + a2 ----------------
__global__ __launch_bounds__(128) void agg1_k(
    const int* __restrict__ row_ptr, const int* __restrict__ csr_src,
    const float* __restrict__ a1s, const float* __restrict__ a1d,
    const float* __restrict__ h1, const float* __restrict__ bias1,
    const float* __restrict__ W2, const float* __restrict__ att_s2, const float* __restrict__ att_d2,
    float* __restrict__ h2, float* __restrict__ a2s, float* __restrict__ a2d) {
  int n = blockIdx.x;
  int tid = threadIdx.x;
  int rs = row_ptr[n], re = row_ptr[n + 1];
  int deg = re - rs;
  __shared__ float red[16][8];
  __shared__ float mh[8], sh[8];
  __shared__ float vrow[128];
  __shared__ float g2[3][40];
  __shared__ float h2row[40];

  int h = tid & 7, i0 = tid >> 3;  // 16 edge-slots x 8 heads
  float adn = a1d[n * 8 + h];
  // phase 1: segment max
  float mx = -1e30f;
  for (int i = i0; i < deg; i += 16) {
    int s = csr_src[rs + i];
    float e = a1s[s * 8 + h] + adn;
    e = (e > 0.f) ? e : NEG * e;
    mx = fmaxf(mx, e);
  }
  red[i0][h] = mx;
  __syncthreads();
  if (tid < 8) {
    float m = -1e30f;
    for (int i = 0; i < 16; ++i) m = fmaxf(m, red[i][tid]);
    mh[tid] = m;
  }
  __syncthreads();
  float mval = mh[h];
  // phase 2: segment sum of exp
  float sm = 0.f;
  for (int i = i0; i < deg; i += 16) {
    int s = csr_src[rs + i];
    float e = a1s[s * 8 + h] + adn;
    e = (e > 0.f) ? e : NEG * e;
    sm += __expf(e - mval);
  }
  red[i0][h] = sm;
  __syncthreads();
  if (tid < 8) {
    float m = 0.f;
    for (int i = 0; i < 16; ++i) m += red[i][tid];
    sh[tid] = m;
  }
  __syncthreads();
  // phase 3: weighted aggregation over 128 feature dims
  int d_ = tid;
  int hh = d_ >> 4;
  float adn2 = a1d[n * 8 + hh];
  float m2 = mh[hh], s2 = sh[hh];
  float acc = 0.f;
  for (int i = 0; i < deg; ++i) {
    int s = csr_src[rs + i];
    float e = a1s[s * 8 + hh] + adn2;
    e = (e > 0.f) ? e : NEG * e;
    float al = __expf(e - m2);
    acc += al * h1[s * 128 + d_];
  }
  acc = acc / (s2 + 1e-16f) + bias1[d_];
  float v = (acc > 0.f) ? acc : (__expf(acc) - 1.0f);  // ELU
  vrow[d_] = v;
  __syncthreads();
  // fused GEMM2 row: h2row[c] = sum_k vrow[k] * W2[k][c]
  int c = tid % 40, sl = tid / 40;
  if (tid < 120) {
    float part = 0.f;
    int k0 = sl * 43, k1 = (sl == 2) ? 128 : (k0 + 43);
    for (int k = k0; k < k1; ++k) part += vrow[k] * W2[k * 40 + c];
    g2[sl][c] = part;
  }
  __syncthreads();
  if (tid < 40) {
    float hv = g2[0][tid] + g2[1][tid] + g2[2][tid];
    h2[n * 40 + tid] = hv;
    h2row[tid] = hv;
  }
  __syncthreads();
  if (tid < 64) {
    float vs = (tid < 40) ? h2row[tid] * att_s2[tid] : 0.f;
    float vd = (tid < 40) ? h2row[tid] * att_d2[tid] : 0.f;
    #pragma unroll
    for (int off = 32; off > 0; off >>= 1) {
      vs += __shfl_down(vs, off);
      vd += __shfl_down(vd, off);
    }
    if (tid == 0) { a2s[n] = vs; a2d[n] = vd; }
  }
}

// ---------------- Layer-2 aggregation + log_softmax ----------------
__global__ __launch_bounds__(64) void agg2_k(
    const int* __restrict__ row_ptr, const int* __restrict__ csr_src,
    const float* __restrict__ a2s, const float* __restrict__ a2d,
    const float* __restrict__ h2, const float* __restrict__ bias2,
    float* __restrict__ out) {
  int n = blockIdx.x;
  int lane = threadIdx.x;
  int rs = row_ptr[n], re = row_ptr[n + 1];
  int deg = re - rs;
  float adn = a2d[n];
  float mx = -1e30f;
  for (int i = lane; i < deg; i += 64) {
    int s = csr_src[rs + i];
    float e = a2s[s] + adn;
    e = (e > 0.f) ? e : NEG * e;
    mx = fmaxf(mx, e);
  }
  #pragma unroll
  for (int off = 32; off > 0; off >>= 1) mx = fmaxf(mx, __shfl_down(mx, off));
  mx = __shfl(mx, 0);
  float sm = 0.f;
  for (int i = lane; i < deg; i += 64) {
    int s = csr_src[rs + i];
    float e = a2s[s] + adn;
    e = (e > 0.f) ? e : NEG * e;
    sm += __expf(e - mx);
  }
  #pragma unroll
  for (int off = 32; off > 0; off >>= 1) sm += __shfl_down(sm, off);
  sm = __shfl(sm, 0);
  float acc = 0.f;
  int c = lane;
  for (int i = 0; i < deg; ++i) {
    int s = csr_src[rs + i];
    float e = a2s[s] + adn;
    e = (e > 0.f) ? e : NEG * e;
    float al = __expf(e - mx);
    float hv = (c < OUT_DIM) ? h2[s * OUT_DIM + c] : 0.f;
    acc += al * hv;
  }
  float v = (c < OUT_DIM) ? (acc / (sm + 1e-16f) + bias2[c]) : -1e30f;
  // log_softmax over the 40 values
  float vm = v;
  #pragma unroll
  for (int off = 32; off > 0; off >>= 1) vm = fmaxf(vm, __shfl_down(vm, off));
  vm = __shfl(vm, 0);
  float ex = (c < OUT_DIM) ? __expf(v - vm) : 0.f;
  float es = ex;
  #pragma unroll
  for (int off = 32; off > 0; off >>= 1) es += __shfl_down(es, off);
  es = __shfl(es, 0);
  if (c < OUT_DIM) out[n * OUT_DIM + c] = v - vm - __logf(es);
}

// ---------------- launch ----------------

extern "C" void kernel_launch(void* const* d_in, const int* in_sizes, int n_in,
                              void* d_out, int out_size, void* d_ws, size_t ws_size,
                              hipStream_t stream) {
  const float* x   = (const float*)d_in[0];
  const float* W1  = (const float*)d_in[1];
  const float* as1 = (const float*)d_in[2];
  const float* ad1 = (const float*)d_in[3];
  const float* b1  = (const float*)d_in[4];
  const float* W2  = (const float*)d_in[5];
  const float* as2 = (const float*)d_in[6];
  const float* ad2 = (const float*)d_in[7];
  const float* b2  = (const float*)d_in[8];
  const int*   ei  = (const int*)d_in[9];
  int N  = in_sizes[0] / IN_DIM;
  int E0 = in_sizes[9] / 2;
  int EP = E0 + N;
  float* out = (float*)d_out;

  char* ws = (char*)d_ws;
  size_t off = 0;
  auto alloc = [&](size_t bytes) {
    char* p = ws + off;
    off += (bytes + 255) & ~size_t(255);
    return p;
  };
  float* h1     = (float*)alloc((size_t)N * 128 * 4);
  float* a1s    = (float*)alloc((size_t)N * 8 * 4);
  float* a1d    = (float*)alloc((size_t)N * 8 * 4);
  float* h2     = (float*)alloc((size_t)N * 40 * 4);
  float* a2s    = (float*)alloc((size_t)N * 4);
  float* a2d    = (float*)alloc((size_t)N * 4);
  int*   degcnt = (int*)alloc((size_t)2 * N * 4);
  int*   rp     = (int*)alloc((size_t)(N + 4) * 4);
  int*   csr    = (int*)alloc((size_t)EP * 4);
  int* deg = degcnt;
  int* cnt = degcnt + N;

  zero_ints<<<(2 * N + 255) / 256, 256, 0, stream>>>(degcnt, 2 * N);
  hist_k<<<(EP + 255) / 256, 256, 0, stream>>>(ei, E0, N, deg);
  scan_k<<<1, 1024, 0, stream>>>(deg, rp, N);
  scatter_k<<<(EP + 255) / 256, 256, 0, stream>>>(ei, E0, N, rp, cnt, csr);
  gemm1_k<<<(N + 127) / 128, 256, 0, stream>>>(x, W1, as1, ad1, h1, a1s, a1d, N);
  agg1_k<<<N, 128, 0, stream>>>(rp, csr, a1s, a1d, h1, b1, W2, as2, ad2, h2, a2s, a2d);
  agg2_k<<<N, 64, 0, stream>>>(rp, csr, a2s, a2d, h2, b2, out);
}